// Round 1
// baseline (1300.471 us; speedup 1.0000x reference)
//
#include <hip/hip_runtime.h>

#define BN 8
#define NN 4096
#define CC 64
#define MM 1024
#define KK 64
#define HH 128

typedef __attribute__((ext_vector_type(8))) short short8;
typedef __attribute__((ext_vector_type(4))) float f32x4;

__device__ inline unsigned short f2bf(float f) {
  union { float f; unsigned u; } v; v.f = f;
  unsigned r = v.u + 0x7FFFu + ((v.u >> 16) & 1u);
  return (unsigned short)(r >> 16);
}

// squared distance with NO fma contraction, numpy op order: (dx*dx + dy*dy) + dz*dz
__device__ inline float sqd(float ax, float ay, float az, float bx, float by, float bz) {
  float dx = __fsub_rn(ax, bx), dy = __fsub_rn(ay, by), dz = __fsub_rn(az, bz);
  return __fadd_rn(__fadd_rn(__fmul_rn(dx, dx), __fmul_rn(dy, dy)), __fmul_rn(dz, dz));
}

// ---------------- weight prep: transpose + pad + bf16 ----------------
// W1 [67][128] -> W1T bf16 [128][104] (k-padded with zeros 67..103)
// W2 [128][128] -> W2T bf16 [128][136] (k-padded 128..135)
__global__ void prep_w(const float* __restrict__ W1, const float* __restrict__ W2,
                       short* __restrict__ W1T, short* __restrict__ W2T) {
  int t = blockIdx.x * 256 + threadIdx.x;
  if (t < 128 * 104) {
    int n = t / 104, k = t % 104;
    float v = (k < 67) ? W1[k * 128 + n] : 0.f;
    W1T[t] = (short)f2bf(v);
  }
  if (t < 128 * 136) {
    int n = t / 136, k = t % 136;
    float v = (k < 128) ? W2[k * 128 + n] : 0.f;
    W2T[t] = (short)f2bf(v);
  }
}

// ---------------- FPS: one block per batch ----------------
__global__ __launch_bounds__(256) void fps_k(const float* __restrict__ pos,
                                             int* __restrict__ fidx,
                                             float* __restrict__ centers) {
  const int b = blockIdx.x;
  const int tid = threadIdx.x;
  const int lane = tid & 63;
  const int wv = tid >> 6;
  __shared__ float sp[NN * 3];
  __shared__ float sv[2][4];
  __shared__ int spi[2][4];

  const float* P = pos + (size_t)b * NN * 3;
  for (int i = tid; i < NN * 3; i += 256) sp[i] = P[i];
  __syncthreads();

  float px[16], py[16], pz[16], mind[16];
#pragma unroll
  for (int i = 0; i < 16; ++i) {
    int p = tid + i * 256;
    px[i] = sp[p * 3 + 0];
    py[i] = sp[p * 3 + 1];
    pz[i] = sp[p * 3 + 2];
  }
  float cx = sp[0], cy = sp[1], cz = sp[2];
#pragma unroll
  for (int i = 0; i < 16; ++i) mind[i] = sqd(px[i], py[i], pz[i], cx, cy, cz);

  if (tid == 0) {
    fidx[b * MM] = 0;
    centers[(size_t)(b * MM) * 3 + 0] = sp[0];
    centers[(size_t)(b * MM) * 3 + 1] = sp[1];
    centers[(size_t)(b * MM) * 3 + 2] = sp[2];
  }

  for (int m = 1; m < MM; ++m) {
    // local argmax (first/lowest index wins on ties: i increasing == p increasing)
    float bv = -1.f;
    int bp = 0;
#pragma unroll
    for (int i = 0; i < 16; ++i) {
      if (mind[i] > bv) { bv = mind[i]; bp = tid + i * 256; }
    }
    // wave butterfly, tie -> lower point index
#pragma unroll
    for (int off = 32; off; off >>= 1) {
      float ov = __shfl_xor(bv, off);
      int op = __shfl_xor(bp, off);
      if (ov > bv || (ov == bv && op < bp)) { bv = ov; bp = op; }
    }
    if (lane == 0) { sv[m & 1][wv] = bv; spi[m & 1][wv] = bp; }
    __syncthreads();
    bv = sv[m & 1][0]; bp = spi[m & 1][0];
#pragma unroll
    for (int w = 1; w < 4; ++w) {
      float ov = sv[m & 1][w];
      int op = spi[m & 1][w];
      if (ov > bv || (ov == bv && op < bp)) { bv = ov; bp = op; }
    }
    cx = sp[bp * 3 + 0]; cy = sp[bp * 3 + 1]; cz = sp[bp * 3 + 2];
    if (tid == 0) {
      fidx[b * MM + m] = bp;
      centers[(size_t)(b * MM + m) * 3 + 0] = cx;
      centers[(size_t)(b * MM + m) * 3 + 1] = cy;
      centers[(size_t)(b * MM + m) * 3 + 2] = cz;
    }
#pragma unroll
    for (int i = 0; i < 16; ++i) {
      float d2 = sqd(px[i], py[i], pz[i], cx, cy, cz);
      mind[i] = fminf(mind[i], d2);
    }
  }
}

// ---------------- fused ball query + PointNetConv MLP: one block per center ----------------
__global__ __launch_bounds__(256) void sa_k(const float* __restrict__ x,
                                            const float* __restrict__ pos,
                                            const float* __restrict__ b1,
                                            const float* __restrict__ b2,
                                            const short* __restrict__ W1T,
                                            const short* __restrict__ W2T,
                                            const int* __restrict__ fidx,
                                            float* __restrict__ out) {
  const int cm = blockIdx.x;      // b*MM + m
  const int b = cm >> 10;         // / MM
  const int tid = threadIdx.x;
  const int lane = tid & 63, wv = tid >> 6;
  const int l15 = lane & 15, lg = lane >> 4;

  __shared__ short s_feat[64][104];
  __shared__ short s_h1[64][136];
  __shared__ int s_nbr[64];
  __shared__ int s_wcnt[4];

  // --- weight fragments in registers (B-operand): row=n (lane&15), k contiguous 8 ---
  const int n0 = wv * 32;
  short8 w1f[2][3], w2f[2][4];
#pragma unroll
  for (int nt = 0; nt < 2; ++nt) {
    int row = n0 + nt * 16 + l15;
#pragma unroll
    for (int kt = 0; kt < 3; ++kt)
      w1f[nt][kt] = *reinterpret_cast<const short8*>(W1T + row * 104 + kt * 32 + lg * 8);
#pragma unroll
    for (int kt = 0; kt < 4; ++kt)
      w2f[nt][kt] = *reinterpret_cast<const short8*>(W2T + row * 136 + kt * 32 + lg * 8);
  }

  const int ci = fidx[cm];
  const float* Pb = pos + (size_t)b * NN * 3;
  const float cx = Pb[ci * 3 + 0], cy = Pb[ci * 3 + 1], cz = Pb[ci * 3 + 2];

  // --- ball query: first KK in index order with d2 <= 0.04f ---
  int cnt = 0;
  for (int base = 0; base < NN; base += 256) {
    int p = base + tid;
    float d2 = sqd(Pb[p * 3 + 0], Pb[p * 3 + 1], Pb[p * 3 + 2], cx, cy, cz);
    bool pred = d2 <= 0.04f;   // float32(0.04), matches reference R*R cast
    unsigned long long mask = __ballot(pred);
    if (lane == 0) s_wcnt[wv] = __popcll(mask);
    __syncthreads();
    int wbase = cnt, tot = 0;
#pragma unroll
    for (int w = 0; w < 4; ++w) {
      int c = s_wcnt[w];
      tot += c;
      if (w < wv) wbase += c;
    }
    if (pred) {
      int slot = wbase + (int)__popcll(mask & ((1ull << lane) - 1ull));
      if (slot < KK) s_nbr[slot] = p;
    }
    cnt += tot;
    __syncthreads();
    if (cnt >= KK) break;
  }
  if (cnt > KK) cnt = KK;

  // --- zero feat (covers padding cols + invalid rows), then gather ---
  {
    int* fz = (int*)&s_feat[0][0];
    for (int i = tid; i < 64 * 104 / 2; i += 256) fz[i] = 0;
  }
  __syncthreads();

  {
    const int j = tid >> 2, q = tid & 3;   // 64 neighbors x 4 thread-chunks of 16 feats
    if (j < cnt) {
      int nj = s_nbr[j];
      const float* xr = x + ((size_t)b * NN + nj) * CC + q * 16;
      unsigned* dst = (unsigned*)&s_feat[j][q * 16];
#pragma unroll
      for (int v4 = 0; v4 < 4; ++v4) {
        f32x4 xv = *reinterpret_cast<const f32x4*>(xr + v4 * 4);
        unsigned lo0 = (unsigned)f2bf(xv[0]) | ((unsigned)f2bf(xv[1]) << 16);
        unsigned lo1 = (unsigned)f2bf(xv[2]) | ((unsigned)f2bf(xv[3]) << 16);
        dst[v4 * 2 + 0] = lo0;
        dst[v4 * 2 + 1] = lo1;
      }
      if (q == 0) {
        s_feat[j][64] = (short)f2bf(__fsub_rn(Pb[nj * 3 + 0], cx));
        s_feat[j][65] = (short)f2bf(__fsub_rn(Pb[nj * 3 + 1], cy));
        s_feat[j][66] = (short)f2bf(__fsub_rn(Pb[nj * 3 + 2], cz));
      }
    }
  }
  __syncthreads();

  // --- layer 1: feat[64x96] @ W1T -> h1[64][128] (per-wave 32 cols) ---
  f32x4 acc[4][2];
#pragma unroll
  for (int mt = 0; mt < 4; ++mt)
#pragma unroll
    for (int nt = 0; nt < 2; ++nt) acc[mt][nt] = (f32x4)0.f;

#pragma unroll
  for (int mt = 0; mt < 4; ++mt) {
    int arow = mt * 16 + l15;
#pragma unroll
    for (int kt = 0; kt < 3; ++kt) {
      short8 af = *reinterpret_cast<const short8*>(&s_feat[arow][kt * 32 + lg * 8]);
      acc[mt][0] = __builtin_amdgcn_mfma_f32_16x16x32_bf16(af, w1f[0][kt], acc[mt][0], 0, 0, 0);
      acc[mt][1] = __builtin_amdgcn_mfma_f32_16x16x32_bf16(af, w1f[1][kt], acc[mt][1], 0, 0, 0);
    }
  }

  // bias + relu -> bf16 h1 in LDS
#pragma unroll
  for (int mt = 0; mt < 4; ++mt) {
#pragma unroll
    for (int nt = 0; nt < 2; ++nt) {
      int col = n0 + nt * 16 + l15;
      float bias = b1[col];
#pragma unroll
      for (int r = 0; r < 4; ++r) {
        int row = mt * 16 + lg * 4 + r;
        float h = fmaxf(__fadd_rn(acc[mt][nt][r], bias), 0.f);
        s_h1[row][col] = (short)f2bf(h);
      }
    }
  }
  __syncthreads();

  // --- layer 2: h1[64x128] @ W2T ---
  f32x4 acc2[4][2];
#pragma unroll
  for (int mt = 0; mt < 4; ++mt)
#pragma unroll
    for (int nt = 0; nt < 2; ++nt) acc2[mt][nt] = (f32x4)0.f;

#pragma unroll
  for (int mt = 0; mt < 4; ++mt) {
    int arow = mt * 16 + l15;
#pragma unroll
    for (int kt = 0; kt < 4; ++kt) {
      short8 af = *reinterpret_cast<const short8*>(&s_h1[arow][kt * 32 + lg * 8]);
      acc2[mt][0] = __builtin_amdgcn_mfma_f32_16x16x32_bf16(af, w2f[0][kt], acc2[mt][0], 0, 0, 0);
      acc2[mt][1] = __builtin_amdgcn_mfma_f32_16x16x32_bf16(af, w2f[1][kt], acc2[mt][1], 0, 0, 0);
    }
  }

  // --- bias + relu + masked max over neighbors, then write out[cm][col] ---
#pragma unroll
  for (int nt = 0; nt < 2; ++nt) {
    int col = n0 + nt * 16 + l15;
    float bias = b2[col];
    float mx = -1e30f;
#pragma unroll
    for (int mt = 0; mt < 4; ++mt) {
#pragma unroll
      for (int r = 0; r < 4; ++r) {
        int row = mt * 16 + lg * 4 + r;
        float h = fmaxf(__fadd_rn(acc2[mt][nt][r], bias), 0.f);
        if (row < cnt) mx = fmaxf(mx, h);
      }
    }
    mx = fmaxf(mx, __shfl_xor(mx, 16));
    mx = fmaxf(mx, __shfl_xor(mx, 32));
    if (lg == 0) out[(size_t)cm * HH + col] = mx;
  }
}

extern "C" void kernel_launch(void* const* d_in, const int* in_sizes, int n_in,
                              void* d_out, int out_size, void* d_ws, size_t ws_size,
                              hipStream_t stream) {
  const float* x = (const float*)d_in[0];
  const float* pos = (const float*)d_in[1];
  const float* W1 = (const float*)d_in[2];
  const float* b1 = (const float*)d_in[3];
  const float* W2 = (const float*)d_in[4];
  const float* b2 = (const float*)d_in[5];

  float* out = (float*)d_out;
  float* centers = out + (size_t)BN * MM * HH;

  char* ws = (char*)d_ws;
  int* fidx = (int*)ws;                              // 8*1024*4 = 32768 B
  short* W1T = (short*)(ws + 32768);                 // 128*104*2 = 26624 B
  short* W2T = (short*)(ws + 32768 + 26624);         // 128*136*2 = 34816 B

  prep_w<<<68, 256, 0, stream>>>(W1, W2, W1T, W2T);
  fps_k<<<BN, 256, 0, stream>>>(pos, fidx, centers);
  sa_k<<<BN * MM, 256, 0, stream>>>(x, pos, b1, b2, W1T, W2T, fidx, out);
}

// Round 2
// 758.607 us; speedup vs baseline: 1.7143x; 1.7143x over previous
//
#include <hip/hip_runtime.h>

#define BN 8
#define NN 4096
#define CC 64
#define MM 1024
#define KK 64
#define HH 128

typedef __attribute__((ext_vector_type(8))) short short8;
typedef __attribute__((ext_vector_type(4))) float f32x4;
typedef unsigned long long u64;
typedef unsigned int u32;

__device__ inline unsigned short f2bf(float f) {
  union { float f; unsigned u; } v; v.f = f;
  unsigned r = v.u + 0x7FFFu + ((v.u >> 16) & 1u);
  return (unsigned short)(r >> 16);
}

// squared distance with NO fma contraction, numpy op order: (dx*dx + dy*dy) + dz*dz
__device__ inline float sqd(float ax, float ay, float az, float bx, float by, float bz) {
  float dx = __fsub_rn(ax, bx), dy = __fsub_rn(ay, by), dz = __fsub_rn(az, bz);
  return __fadd_rn(__fadd_rn(__fmul_rn(dx, dx), __fmul_rn(dy, dy)), __fmul_rn(dz, dz));
}

// ---------------- weight prep: transpose + pad + bf16 ----------------
__global__ void prep_w(const float* __restrict__ W1, const float* __restrict__ W2,
                       short* __restrict__ W1T, short* __restrict__ W2T) {
  int t = blockIdx.x * 256 + threadIdx.x;
  if (t < 128 * 104) {
    int n = t / 104, k = t % 104;
    float v = (k < 67) ? W1[k * 128 + n] : 0.f;
    W1T[t] = (short)f2bf(v);
  }
  if (t < 128 * 136) {
    int n = t / 136, k = t % 136;
    float v = (k < 128) ? W2[k * 128 + n] : 0.f;
    W2T[t] = (short)f2bf(v);
  }
}

// ---- DPP-based wave max of u64 key (result broadcast via readlane 63) ----
template <int CTRL, int RM>
__device__ __forceinline__ u64 dpp_mv(u64 k) {
  int lo = __builtin_amdgcn_update_dpp(0, (int)(u32)k, CTRL, RM, 0xF, false);
  int hi = __builtin_amdgcn_update_dpp(0, (int)(u32)(k >> 32), CTRL, RM, 0xF, false);
  return ((u64)(u32)hi << 32) | (u32)lo;
}

__device__ __forceinline__ u64 wave_kmax(u64 k) {
  u64 m;
  m = dpp_mv<0xB1, 0xF>(k); if (m > k) k = m;   // quad_perm [1,0,3,2]  (xor 1)
  m = dpp_mv<0x4E, 0xF>(k); if (m > k) k = m;   // quad_perm [2,3,0,1]  (xor 2)
  m = dpp_mv<0x141, 0xF>(k); if (m > k) k = m;  // row_half_mirror      (xor 4-ish)
  m = dpp_mv<0x140, 0xF>(k); if (m > k) k = m;  // row_mirror           (xor 8-ish)
  m = dpp_mv<0x142, 0xA>(k); if (m > k) k = m;  // row_bcast15 -> rows 1,3
  m = dpp_mv<0x143, 0xC>(k); if (m > k) k = m;  // row_bcast31 -> rows 2,3
  u32 lo = (u32)__builtin_amdgcn_readlane((int)(u32)k, 63);
  u32 hi = (u32)__builtin_amdgcn_readlane((int)(u32)(k >> 32), 63);
  return ((u64)hi << 32) | lo;
}

// ---------------- FPS: one block per batch ----------------
__global__ __launch_bounds__(256) void fps_k(const float* __restrict__ pos,
                                             float* __restrict__ centers) {
  const int b = blockIdx.x;
  const int tid = threadIdx.x;
  const int lane = tid & 63;
  const int wv = tid >> 6;
  __shared__ f32x4 sp4[NN];
  __shared__ u64 sk[2][4];

  const float* P = pos + (size_t)b * NN * 3;

  float px[16], py[16], pz[16], mind[16];
  u32 klo[16];
#pragma unroll
  for (int i = 0; i < 16; ++i) {
    int p = tid + i * 256;
    px[i] = P[p * 3 + 0];
    py[i] = P[p * 3 + 1];
    pz[i] = P[p * 3 + 2];
    klo[i] = ~(u32)p;
    f32x4 v; v[0] = px[i]; v[1] = py[i]; v[2] = pz[i]; v[3] = 0.f;
    sp4[p] = v;
  }
  // pin positions in VGPRs — forbid LDS/global rematerialization in the loop
#pragma unroll
  for (int i = 0; i < 16; ++i)
    asm volatile("" : "+v"(px[i]), "+v"(py[i]), "+v"(pz[i]));

  const float c0x = P[0], c0y = P[1], c0z = P[2];
#pragma unroll
  for (int i = 0; i < 16; ++i) mind[i] = sqd(px[i], py[i], pz[i], c0x, c0y, c0z);

  if (tid == 0) {
    centers[(size_t)(b * MM) * 3 + 0] = c0x;
    centers[(size_t)(b * MM) * 3 + 1] = c0y;
    centers[(size_t)(b * MM) * 3 + 2] = c0z;
  }
  __syncthreads();   // sp4 visible to all

  for (int m = 1; m < MM; ++m) {
    // local argmax as packed keys: (dist_bits<<32) | ~idx  => max = max dist, tie -> lowest idx
    u64 k[16];
#pragma unroll
    for (int i = 0; i < 16; ++i)
      k[i] = ((u64)__float_as_uint(mind[i]) << 32) | klo[i];
#pragma unroll
    for (int s = 8; s; s >>= 1)
#pragma unroll
      for (int i = 0; i < s; ++i)
        if (k[i + s] > k[i]) k[i] = k[i + s];

    u64 kw = wave_kmax(k[0]);          // uniform across wave
    if (lane == 0) sk[m & 1][wv] = kw;
    __syncthreads();
    u64 kb = sk[m & 1][0];
#pragma unroll
    for (int w = 1; w < 4; ++w) {
      u64 o = sk[m & 1][w];
      if (o > kb) kb = o;
    }
    const u32 bp = ~(u32)kb;           // selected point index
    const f32x4 c4 = sp4[bp];
    if (tid == 0) {
      centers[(size_t)(b * MM + m) * 3 + 0] = c4[0];
      centers[(size_t)(b * MM + m) * 3 + 1] = c4[1];
      centers[(size_t)(b * MM + m) * 3 + 2] = c4[2];
    }
#pragma unroll
    for (int i = 0; i < 16; ++i) {
      float d2 = sqd(px[i], py[i], pz[i], c4[0], c4[1], c4[2]);
      mind[i] = fminf(mind[i], d2);
    }
  }
}

// ---------------- fused ball query + PointNetConv MLP: one block per center ----------------
__global__ __launch_bounds__(256) void sa_k(const float* __restrict__ x,
                                            const float* __restrict__ pos,
                                            const float* __restrict__ b1,
                                            const float* __restrict__ b2,
                                            const short* __restrict__ W1T,
                                            const short* __restrict__ W2T,
                                            const float* __restrict__ centers,
                                            float* __restrict__ out) {
  const int cm = blockIdx.x;      // b*MM + m
  const int b = cm >> 10;         // / MM
  const int tid = threadIdx.x;
  const int lane = tid & 63, wv = tid >> 6;
  const int l15 = lane & 15, lg = lane >> 4;

  __shared__ short s_feat[64][104];
  __shared__ short s_h1[64][136];
  __shared__ int s_nbr[64];
  __shared__ int s_wcnt[4];

  // --- weight fragments in registers (B-operand): row=n (lane&15), k contiguous 8 ---
  const int n0 = wv * 32;
  short8 w1f[2][3], w2f[2][4];
#pragma unroll
  for (int nt = 0; nt < 2; ++nt) {
    int row = n0 + nt * 16 + l15;
#pragma unroll
    for (int kt = 0; kt < 3; ++kt)
      w1f[nt][kt] = *reinterpret_cast<const short8*>(W1T + row * 104 + kt * 32 + lg * 8);
#pragma unroll
    for (int kt = 0; kt < 4; ++kt)
      w2f[nt][kt] = *reinterpret_cast<const short8*>(W2T + row * 136 + kt * 32 + lg * 8);
  }

  const float* Pb = pos + (size_t)b * NN * 3;
  const float cx = centers[(size_t)cm * 3 + 0];
  const float cy = centers[(size_t)cm * 3 + 1];
  const float cz = centers[(size_t)cm * 3 + 2];

  // --- ball query: first KK in index order with d2 <= 0.04f ---
  int cnt = 0;
  for (int base = 0; base < NN; base += 256) {
    int p = base + tid;
    float d2 = sqd(Pb[p * 3 + 0], Pb[p * 3 + 1], Pb[p * 3 + 2], cx, cy, cz);
    bool pred = d2 <= 0.04f;   // float32(0.04), matches reference R*R cast
    unsigned long long mask = __ballot(pred);
    if (lane == 0) s_wcnt[wv] = __popcll(mask);
    __syncthreads();
    int wbase = cnt, tot = 0;
#pragma unroll
    for (int w = 0; w < 4; ++w) {
      int c = s_wcnt[w];
      tot += c;
      if (w < wv) wbase += c;
    }
    if (pred) {
      int slot = wbase + (int)__popcll(mask & ((1ull << lane) - 1ull));
      if (slot < KK) s_nbr[slot] = p;
    }
    cnt += tot;
    __syncthreads();
    if (cnt >= KK) break;
  }
  if (cnt > KK) cnt = KK;

  // --- zero feat (covers padding cols + invalid rows), then gather ---
  {
    int* fz = (int*)&s_feat[0][0];
    for (int i = tid; i < 64 * 104 / 2; i += 256) fz[i] = 0;
  }
  __syncthreads();

  {
    const int j = tid >> 2, q = tid & 3;   // 64 neighbors x 4 thread-chunks of 16 feats
    if (j < cnt) {
      int nj = s_nbr[j];
      const float* xr = x + ((size_t)b * NN + nj) * CC + q * 16;
      unsigned* dst = (unsigned*)&s_feat[j][q * 16];
#pragma unroll
      for (int v4 = 0; v4 < 4; ++v4) {
        f32x4 xv = *reinterpret_cast<const f32x4*>(xr + v4 * 4);
        unsigned lo0 = (unsigned)f2bf(xv[0]) | ((unsigned)f2bf(xv[1]) << 16);
        unsigned lo1 = (unsigned)f2bf(xv[2]) | ((unsigned)f2bf(xv[3]) << 16);
        dst[v4 * 2 + 0] = lo0;
        dst[v4 * 2 + 1] = lo1;
      }
      if (q == 0) {
        s_feat[j][64] = (short)f2bf(__fsub_rn(Pb[nj * 3 + 0], cx));
        s_feat[j][65] = (short)f2bf(__fsub_rn(Pb[nj * 3 + 1], cy));
        s_feat[j][66] = (short)f2bf(__fsub_rn(Pb[nj * 3 + 2], cz));
      }
    }
  }
  __syncthreads();

  // --- layer 1: feat[64x96] @ W1T -> h1[64][128] (per-wave 32 cols) ---
  f32x4 acc[4][2];
#pragma unroll
  for (int mt = 0; mt < 4; ++mt)
#pragma unroll
    for (int nt = 0; nt < 2; ++nt) acc[mt][nt] = (f32x4)0.f;

#pragma unroll
  for (int mt = 0; mt < 4; ++mt) {
    int arow = mt * 16 + l15;
#pragma unroll
    for (int kt = 0; kt < 3; ++kt) {
      short8 af = *reinterpret_cast<const short8*>(&s_feat[arow][kt * 32 + lg * 8]);
      acc[mt][0] = __builtin_amdgcn_mfma_f32_16x16x32_bf16(af, w1f[0][kt], acc[mt][0], 0, 0, 0);
      acc[mt][1] = __builtin_amdgcn_mfma_f32_16x16x32_bf16(af, w1f[1][kt], acc[mt][1], 0, 0, 0);
    }
  }

  // bias + relu -> bf16 h1 in LDS
#pragma unroll
  for (int mt = 0; mt < 4; ++mt) {
#pragma unroll
    for (int nt = 0; nt < 2; ++nt) {
      int col = n0 + nt * 16 + l15;
      float bias = b1[col];
#pragma unroll
      for (int r = 0; r < 4; ++r) {
        int row = mt * 16 + lg * 4 + r;
        float h = fmaxf(__fadd_rn(acc[mt][nt][r], bias), 0.f);
        s_h1[row][col] = (short)f2bf(h);
      }
    }
  }
  __syncthreads();

  // --- layer 2: h1[64x128] @ W2T ---
  f32x4 acc2[4][2];
#pragma unroll
  for (int mt = 0; mt < 4; ++mt)
#pragma unroll
    for (int nt = 0; nt < 2; ++nt) acc2[mt][nt] = (f32x4)0.f;

#pragma unroll
  for (int mt = 0; mt < 4; ++mt) {
    int arow = mt * 16 + l15;
#pragma unroll
    for (int kt = 0; kt < 4; ++kt) {
      short8 af = *reinterpret_cast<const short8*>(&s_h1[arow][kt * 32 + lg * 8]);
      acc2[mt][0] = __builtin_amdgcn_mfma_f32_16x16x32_bf16(af, w2f[0][kt], acc2[mt][0], 0, 0, 0);
      acc2[mt][1] = __builtin_amdgcn_mfma_f32_16x16x32_bf16(af, w2f[1][kt], acc2[mt][1], 0, 0, 0);
    }
  }

  // --- bias + relu + masked max over neighbors, then write out[cm][col] ---
#pragma unroll
  for (int nt = 0; nt < 2; ++nt) {
    int col = n0 + nt * 16 + l15;
    float bias = b2[col];
    float mx = -1e30f;
#pragma unroll
    for (int mt = 0; mt < 4; ++mt) {
#pragma unroll
      for (int r = 0; r < 4; ++r) {
        int row = mt * 16 + lg * 4 + r;
        float h = fmaxf(__fadd_rn(acc2[mt][nt][r], bias), 0.f);
        if (row < cnt) mx = fmaxf(mx, h);
      }
    }
    mx = fmaxf(mx, __shfl_xor(mx, 16));
    mx = fmaxf(mx, __shfl_xor(mx, 32));
    if (lg == 0) out[(size_t)cm * HH + col] = mx;
  }
}

extern "C" void kernel_launch(void* const* d_in, const int* in_sizes, int n_in,
                              void* d_out, int out_size, void* d_ws, size_t ws_size,
                              hipStream_t stream) {
  const float* x = (const float*)d_in[0];
  const float* pos = (const float*)d_in[1];
  const float* W1 = (const float*)d_in[2];
  const float* b1 = (const float*)d_in[3];
  const float* W2 = (const float*)d_in[4];
  const float* b2 = (const float*)d_in[5];

  float* out = (float*)d_out;
  float* centers = out + (size_t)BN * MM * HH;

  char* ws = (char*)d_ws;
  short* W1T = (short*)ws;                    // 128*104*2 = 26624 B
  short* W2T = (short*)(ws + 26624);          // 128*136*2 = 34816 B

  prep_w<<<68, 256, 0, stream>>>(W1, W2, W1T, W2T);
  fps_k<<<BN, 256, 0, stream>>>(pos, centers);
  sa_k<<<BN * MM, 256, 0, stream>>>(x, pos, b1, b2, W1T, W2T, centers, out);
}